// Round 1
// baseline (162.876 us; speedup 1.0000x reference)
//
#include <hip/hip_runtime.h>
#include <math.h>

// Problem constants (fixed by reference: enc (32,64,64,64) fp32, embed (512,64) fp32)
#define DQ 64
#define KQ 512
#define NVEC 131072
#define QOUT_SIZE (NVEC * DQ)              // 8388608
#define LOSS_OFF QOUT_SIZE
#define IDX_OFF (QOUT_SIZE + 1)

#define RPW 32                             // rows per wave (2 MFMA A-tiles)
#define WPB 2                              // waves per block (128 threads)
#define VPB (RPW * WPB)                    // 64 rows per block
#define NBLK (NVEC / VPB)                  // 2048 blocks -> 8 per CU
#define SC 64                              // codes per LDS stage
#define NST (KQ / SC)                      // 8 stages
#define SDQ (SC * DQ)                      // 4096 halfs per stage buffer (8 KB)
// fp16 single-product d2 error: 2*(x.e - xh.eh), std ~6.4e-3, pairwise ~9e-3.
// THR = 0.05 ~ 5.5 sigma; measured top-2 gap scale ~6 -> rescan ~0.8% of rows.
#define TIE_THR 0.05f

typedef __attribute__((ext_vector_type(8))) _Float16 half8;        // 8 f16 = 1 MFMA A/B frag
typedef __attribute__((ext_vector_type(4))) float f32x4;           // MFMA C/D frag

static __device__ __forceinline__ void cvt8h(float4 a, float4 b, half8& h) {
    // RNE f32->f16 (v_cvt_f16_f32 default mode). Do NOT use pkrtz (RTZ doubles err).
    h[0] = (_Float16)a.x; h[1] = (_Float16)a.y; h[2] = (_Float16)a.z; h[3] = (_Float16)a.w;
    h[4] = (_Float16)b.x; h[5] = (_Float16)b.y; h[6] = (_Float16)b.z; h[7] = (_Float16)b.w;
}

// Init: fp16 codebook in XOR-SWIZZLED layout (chunk c of row k stored at slot
// c ^ (k&7)) so main-kernel ds_read_b128 B-frag reads are conflict-light while
// staging stays a verbatim contiguous copy. Plus exact fp32 e_sq + loss=0.
__global__ void vq_init_kernel(const float* __restrict__ embed,
                               unsigned short* __restrict__ eh,
                               float* __restrict__ esq,
                               float* __restrict__ out) {
    const int t = blockIdx.x * 64 + threadIdx.x;   // 0..4095
    if (t == 0) out[LOSS_OFF] = 0.0f;
    const int k = t >> 3;            // codebook row
    const int c = t & 7;             // 16-byte chunk (8 dims)
    const float4* p = (const float4*)(embed + (size_t)k * DQ + c * 8);
    float4 a = p[0], b = p[1];
    half8 h;
    cvt8h(a, b, h);
    const int slot = c ^ (k & 7);    // XOR swizzle
    *(half8*)(eh + (size_t)k * DQ + slot * 8) = h;

    float ps = 0.f;
    ps = fmaf(a.x, a.x, ps); ps = fmaf(a.y, a.y, ps); ps = fmaf(a.z, a.z, ps); ps = fmaf(a.w, a.w, ps);
    ps = fmaf(b.x, b.x, ps); ps = fmaf(b.y, b.y, ps); ps = fmaf(b.z, b.z, ps); ps = fmaf(b.w, b.w, ps);
    ps += __shfl_xor(ps, 1);
    ps += __shfl_xor(ps, 2);
    ps += __shfl_xor(ps, 4);
    if (c == 0) esq[k] = ps;
}

// R13: counters showed ~1 WG/CU resident (Occupancy 13.4% ~= 4.3 waves/CU) and
// a serial-latency model reproduces the 76 us — the R12 "4 WGs/CU" never
// materialized. Restructure: (1) fp16 single-product replaces bf16 hi/lo
// (MFMA 3x fewer, acc dep chain 6->2, no lo codebook: LDS stage + staging
// loads + B regs halve; exact-fp64 tie rescan with THR=0.05 keeps indices
// exact); (2) 2-wave/128-thread blocks, VPB=64 -> 2048 WGs, ~19 KB LDS ->
// 8 WGs/CU, decorrelated barriers. Allocator rule (R12): provable waves/SIMD
// = min(LDS WGs=8, slots) * 2 / 4 = 4 -> VGPR budget 128; kernel ~100, no
// spill. R6-R9 lesson kept: no global loads in the k-loop (LDS-staged
// codebook, dbuf, reg-prefetch two stages ahead). R3 lesson kept: VGPR arrays
// only indexed by fully-unrolled constants.
__global__ __launch_bounds__(128) void vq_mfma_kernel(const float* __restrict__ enc,
                                                      const float* __restrict__ embed,
                                                      const unsigned short* __restrict__ eh,
                                                      const float* __restrict__ esq,
                                                      float* __restrict__ out) {
    __shared__ unsigned short hs[2 * SDQ];     // fp16 stages (dbuf): 16 KB
    __shared__ float esq_s[KQ];                // 2 KB
    __shared__ int bidx_s[VPB];                // 256 B
    __shared__ int flag_s[VPB];                // 256 B
    __shared__ float red[WPB];

    const int tid = threadIdx.x;               // 0..127
    const int lane = tid & 63;
    const int w = tid >> 6;                    // wave 0..1
    const int l15 = lane & 15;
    const int l4 = lane >> 4;                  // 0..3
    const int vb = blockIdx.x * VPB + w * RPW;

    esq_s[tid]       = esq[tid];
    esq_s[tid + 128] = esq[tid + 128];
    esq_s[tid + 256] = esq[tid + 256];
    esq_s[tid + 384] = esq[tid + 384];

    // A fragments for 2 tiles: row m = l15 (+a*16), k-chunks l4*8 and 32+l4*8.
    half8 ahA[2], ahB[2];
#pragma unroll
    for (int a = 0; a < 2; a++) {
        const float* base = enc + (size_t)(vb + a * 16 + l15) * DQ + l4 * 8;
        const float4* p0 = (const float4*)base;
        const float4* p1 = (const float4*)(base + 32);
        cvt8h(p0[0], p0[1], ahA[a]);
        cvt8h(p1[0], p1[1], ahB[a]);
    }

    float m1[8], m2[8];
    int i1[8];
#pragma unroll
    for (int r = 0; r < 8; r++) { m1[r] = 3.4e38f; m2[r] = 3.4e38f; i1[r] = 0; }

    // Swizzled B-frag slot offsets (elements); key = l15&7.
    const int sl0 = (l4 ^ (l15 & 7)) * 8;    // chunk l4     (dims l4*8..+8)
    const int sl1 = sl0 ^ 32;                // chunk 4+l4   (dims 32+l4*8..+8)

    // Staging: thread stages 64 B per stage (4 b128 writes; consecutive 16B
    // groups -> 2-way max = free).
    half8 r0 = *(const half8*)(eh + tid * 8);
    half8 r1 = *(const half8*)(eh + 1024 + tid * 8);
    half8 r2 = *(const half8*)(eh + 2048 + tid * 8);
    half8 r3 = *(const half8*)(eh + 3072 + tid * 8);
    // write stage 0 into buf 0
    *(half8*)(hs + tid * 8) = r0;        *(half8*)(hs + 1024 + tid * 8) = r1;
    *(half8*)(hs + 2048 + tid * 8) = r2; *(half8*)(hs + 3072 + tid * 8) = r3;
    // prefetch stage 1 into regs
    r0 = *(const half8*)(eh + SDQ + tid * 8);
    r1 = *(const half8*)(eh + SDQ + 1024 + tid * 8);
    r2 = *(const half8*)(eh + SDQ + 2048 + tid * 8);
    r3 = *(const half8*)(eh + SDQ + 3072 + tid * 8);

#define LDB(B0, B1, S) { const int _o = ((S) * 16 + l15) * DQ; \
    B0 = *(const half8*)(hb + _o + sl0); B1 = *(const half8*)(hb + _o + sl1); }

#define BODY(ST, S, B0, B1) { \
    const int code = (ST) * SC + (S) * 16 + l15; \
    const float ev = esq_s[code]; \
    _Pragma("unroll") \
    for (int a = 0; a < 2; a++) { \
        f32x4 acc = {0.f, 0.f, 0.f, 0.f}; \
        acc = __builtin_amdgcn_mfma_f32_16x16x32_f16(ahA[a], B0, acc, 0, 0, 0); \
        acc = __builtin_amdgcn_mfma_f32_16x16x32_f16(ahB[a], B1, acc, 0, 0, 0); \
        _Pragma("unroll") \
        for (int r = 0; r < 4; r++) { \
            float v = fmaf(-2.0f, acc[r], ev); \
            bool lt = v < m1[a * 4 + r]; \
            i1[a * 4 + r] = lt ? code : i1[a * 4 + r]; \
            m2[a * 4 + r] = fminf(m2[a * 4 + r], fmaxf(m1[a * 4 + r], v)); \
            m1[a * 4 + r] = fminf(m1[a * 4 + r], v); \
        } \
    } }

    for (int st = 0; st < NST; st++) {
        // Drains: LDS writes of buf[st&1] (done last iter) + global loads
        // issued last iter (they had a full stage of compute cover).
        __syncthreads();
        if (st < NST - 1) {                  // write stage st+1 into other buf
            unsigned short* hw = hs + ((st + 1) & 1) * SDQ;
            *(half8*)(hw + tid * 8) = r0;        *(half8*)(hw + 1024 + tid * 8) = r1;
            *(half8*)(hw + 2048 + tid * 8) = r2; *(half8*)(hw + 3072 + tid * 8) = r3;
        }
        if (st < NST - 2) {                  // prefetch stage st+2 (overlaps compute)
            const int o = (st + 2) * SDQ;
            r0 = *(const half8*)(eh + o + tid * 8);
            r1 = *(const half8*)(eh + o + 1024 + tid * 8);
            r2 = *(const half8*)(eh + o + 2048 + tid * 8);
            r3 = *(const half8*)(eh + o + 3072 + tid * 8);
        }
        const unsigned short* hb = hs + (st & 1) * SDQ;
        // 4 tiles, even/odd B double-buffer in regs (pure LDS->MFMA->VALU)
        half8 b0h0, b0h1, b1h0, b1h1;
        LDB(b0h0, b0h1, 0)
        LDB(b1h0, b1h1, 1)
        BODY(st, 0, b0h0, b0h1)
        LDB(b0h0, b0h1, 2)
        BODY(st, 1, b1h0, b1h1)
        LDB(b1h0, b1h1, 3)
        BODY(st, 2, b0h0, b0h1)
        BODY(st, 3, b1h0, b1h1)
    }
#undef LDB
#undef BODY

    // Cross-lane merge over the 16 cols (xor on lane&15 bits).
#pragma unroll
    for (int m = 1; m <= 8; m <<= 1) {
#pragma unroll
        for (int r = 0; r < 8; r++) {
            float o1 = __shfl_xor(m1[r], m);
            float o2 = __shfl_xor(m2[r], m);
            int oi = __shfl_xor(i1[r], m);
            float nm2 = fminf(fminf(m2[r], o2), fmaxf(m1[r], o1));
            bool lt = o1 < m1[r];
            i1[r] = lt ? oi : i1[r];
            m1[r] = fminf(m1[r], o1);
            m2[r] = nm2;
        }
    }

    if (l15 == 0) {
#pragma unroll
        for (int a = 0; a < 2; a++)
#pragma unroll
            for (int r = 0; r < 4; r++) {
                const int row = a * 16 + l4 * 4 + r;
                bidx_s[w * RPW + row] = i1[a * 4 + r];
                flag_s[w * RPW + row] = (m2[a * 4 + r] - m1[a * 4 + r] < TIE_THR) ? 1 : 0;
            }
    }
    // bidx_s/flag_s are per-wave segments -> wave-internal visibility only.

    // Exact fp64 rescan of flagged rows (wave-uniform branch; ~0.8% of rows).
    for (int row = 0; row < RPW; row++) {
        if (flag_s[w * RPW + row]) {
            const int v = vb + row;
            const float4* xe = (const float4*)(enc + (size_t)v * DQ);
            unsigned long long best = ~0ULL;
            for (int q = 0; q < 8; q++) {
                const int c = lane * 8 + q;
                const float4* ee = (const float4*)(embed + (size_t)c * DQ);
                double a = 0.0;
                for (int j = 0; j < 16; j++) {          // global ptrs: runtime j fine
                    float4 xx = xe[j], ez = ee[j];
                    double d0 = (double)xx.x - (double)ez.x; a = fma(d0, d0, a);
                    double d1 = (double)xx.y - (double)ez.y; a = fma(d1, d1, a);
                    double d2 = (double)xx.z - (double)ez.z; a = fma(d2, d2, a);
                    double d3 = (double)xx.w - (double)ez.w; a = fma(d3, d3, a);
                }
                unsigned long long p =
                    (((unsigned long long)__double_as_longlong(a)) & ~511ULL) | (unsigned)c;
                best = (p < best) ? p : best;
            }
#pragma unroll
            for (int mm = 1; mm < 64; mm <<= 1) {
                unsigned long long ob = (unsigned long long)__shfl_xor((long long)best, mm);
                best = (ob < best) ? ob : best;
            }
            if (lane == 0) bidx_s[w * RPW + row] = (int)(best & 511ULL);
        }
    }

    // Epilogue: per tile a, lane handles row a*16+l15, chunks l4*8 and 32+l4*8.
    // x recomputed from the fp16 frags (2^-11 rel err; loss-only, bias ~1e-7).
    float lsum = 0.f;
#pragma unroll
    for (int a = 0; a < 2; a++) {
        const int myv = vb + a * 16 + l15;
        const int qb = bidx_s[w * RPW + a * 16 + l15];
        const float* qbase = embed + (size_t)qb * DQ + l4 * 8;
        const float4* qa = (const float4*)qbase;
        const float4* qc = (const float4*)(qbase + 32);
        float4 q0 = qa[0], q1 = qa[1], q2 = qc[0], q3 = qc[1];
        float* obase = out + (size_t)myv * DQ + l4 * 8;
        ((float4*)obase)[0] = q0; ((float4*)obase)[1] = q1;
        ((float4*)(obase + 32))[0] = q2; ((float4*)(obase + 32))[1] = q3;
        if (l4 == 0) out[IDX_OFF + myv] = (float)qb;

        float d;
        d = q0.x - (float)ahA[a][0]; lsum = fmaf(d, d, lsum);
        d = q0.y - (float)ahA[a][1]; lsum = fmaf(d, d, lsum);
        d = q0.z - (float)ahA[a][2]; lsum = fmaf(d, d, lsum);
        d = q0.w - (float)ahA[a][3]; lsum = fmaf(d, d, lsum);
        d = q1.x - (float)ahA[a][4]; lsum = fmaf(d, d, lsum);
        d = q1.y - (float)ahA[a][5]; lsum = fmaf(d, d, lsum);
        d = q1.z - (float)ahA[a][6]; lsum = fmaf(d, d, lsum);
        d = q1.w - (float)ahA[a][7]; lsum = fmaf(d, d, lsum);
        d = q2.x - (float)ahB[a][0]; lsum = fmaf(d, d, lsum);
        d = q2.y - (float)ahB[a][1]; lsum = fmaf(d, d, lsum);
        d = q2.z - (float)ahB[a][2]; lsum = fmaf(d, d, lsum);
        d = q2.w - (float)ahB[a][3]; lsum = fmaf(d, d, lsum);
        d = q3.x - (float)ahB[a][4]; lsum = fmaf(d, d, lsum);
        d = q3.y - (float)ahB[a][5]; lsum = fmaf(d, d, lsum);
        d = q3.z - (float)ahB[a][6]; lsum = fmaf(d, d, lsum);
        d = q3.w - (float)ahB[a][7]; lsum = fmaf(d, d, lsum);
    }

#pragma unroll
    for (int off = 32; off > 0; off >>= 1) lsum += __shfl_down(lsum, off);
    if (lane == 0) red[w] = lsum;
    __syncthreads();
    if (tid == 0) {
        float s = red[0] + red[1];
        atomicAdd(out + LOSS_OFF, s * (2.0f / (float)QOUT_SIZE));
    }
}

extern "C" void kernel_launch(void* const* d_in, const int* in_sizes, int n_in,
                              void* d_out, int out_size, void* d_ws, size_t ws_size,
                              hipStream_t stream) {
    const float* enc = (const float*)d_in[0];
    const float* embed = (const float*)d_in[1];
    float* out = (float*)d_out;
    // ws layout: eh[512*64] u16 | esq[512] f32  (~66 KB)
    unsigned short* eh = (unsigned short*)d_ws;
    float* esq = (float*)(eh + KQ * DQ);

    hipLaunchKernelGGL(vq_init_kernel, dim3(64), dim3(64), 0, stream,
                       embed, eh, esq, out);
    hipLaunchKernelGGL(vq_mfma_kernel, dim3(NBLK), dim3(128), 0, stream,
                       enc, embed, eh, esq, out);
}